// Round 3
// baseline (132.875 us; speedup 1.0000x reference)
//
#include <hip/hip_runtime.h>

typedef unsigned short u16;
typedef unsigned int u32;
typedef __attribute__((ext_vector_type(8))) short short8;   // 8 bf16 (4 VGPRs)
typedef __attribute__((ext_vector_type(4))) float f32x4;

// ws layout (bytes), all 16B-aligned
#define WS_BIAS 0        // float[30*96]
#define WS_W0F 11520     // u16[6*64*8]
#define WS_W1F 17664     // u16[18*64*8]
#define WS_W2F 36096     // u16[18*64*8]

__device__ __forceinline__ u16 f2b(float f) {  // RNE f32 -> bf16
  union { float f; u32 i; } v; v.f = f;
  u32 i = v.i;
  return (u16)((i + 0x7FFFu + ((i >> 16) & 1u)) >> 16);
}
__device__ __forceinline__ u32 pk2(float a, float b) {
  return (u32)f2b(a) | ((u32)f2b(b) << 16);
}

// DS-queue drain that is ALSO a compiler memory fence (asm memory clobber).
__device__ __forceinline__ void lds_fence_lgkm0() {
  asm volatile("s_waitcnt lgkmcnt(0)" ::: "memory");
}

// Inputs are FP32 storage (bf16-rounded values). Build:
// (1) per-(o,d) layer-1 bias table (augmented unit90 = 1.0), fp32;
// (2) weight fragments (bf16) pre-permuted into MFMA frag order.
// Biases b1/b2 folded in as augmented K-row 90.
__global__ void prep_kernel(const float* __restrict__ ac, const float* __restrict__ W0,
                            const float* __restrict__ b0, const float* __restrict__ W1,
                            const float* __restrict__ b1, const float* __restrict__ W2,
                            const float* __restrict__ b2,
                            float* __restrict__ biasTab, u16* __restrict__ W0f,
                            u16* __restrict__ W1f, u16* __restrict__ W2f) {
  int tid = blockIdx.x * blockDim.x + threadIdx.x;
  int nth = gridDim.x * blockDim.x;
  // biasTab[od][u] = b0[u] + c0*W0[4][u] + c1*W0[6][u];  u==90 -> 1.0 (bias lane)
  for (int i = tid; i < 30 * 96; i += nth) {
    int od = i / 96, u = i % 96;
    float v;
    if (u < 90) {
      float c0 = ac[od * 2 + 0], c1 = ac[od * 2 + 1];
      v = b0[u] + c0 * W0[4 * 90 + u] + c1 * W0[6 * 90 + u];
    } else {
      v = (u == 90) ? 1.0f : 0.0f;
    }
    biasTab[i] = v;
  }
  // W0f: A-operand A[m=unit][k=tap], tap order {xw0..xw4} -> W0 rows {5,0,1,2,3}
  for (int i = tid; i < 6 * 64 * 8; i += nth) {
    int jj = i & 7, lane = (i >> 3) & 63, t = i >> 9;
    int q = lane >> 4, m = lane & 15;
    int k = q * 8 + jj;          // tap within K=32 (only k<5 real)
    int u = t * 16 + m;          // output unit
    u16 v = 0;
    if (k < 5 && u < 90) {
      const int rowmap[5] = {5, 0, 1, 2, 3};
      v = f2b(W0[rowmap[k] * 90 + u]);
    }
    W0f[i] = v;
  }
  // W1f (A-operand, L2) / W2f (B-operand, L3): same (lane,jj)->(k,col) map:
  // value = Waug(k = ki*32 + q*8 + jj, col = t*16 + (lane&15)); row 90 = bias, (90,90)=1
  for (int i = tid; i < 2 * 18 * 64 * 8; i += nth) {
    int which = i / (18 * 64 * 8);
    int j2 = i % (18 * 64 * 8);
    int jj = j2 & 7, lane = (j2 >> 3) & 63, f = j2 >> 9;
    int t = f / 3, ki = f % 3;
    int q = lane >> 4, m = lane & 15;
    int k = ki * 32 + q * 8 + jj;
    int col = t * 16 + m;
    const float* W = which ? W2 : W1;
    const float* bb = which ? b2 : b1;
    u16 v = 0;
    if (k < 90 && col < 90) v = f2b(W[k * 90 + col]);
    else if (k == 90) v = (col < 90) ? f2b(bb[col]) : ((col == 90) ? (u16)0x3F80 : (u16)0);
    (which ? W2f : W1f)[j2] = v;
  }
}

__device__ __forceinline__ f32x4 mfma16(short8 a, short8 b, f32x4 c) {
  return __builtin_amdgcn_mfma_f32_16x16x32_bf16(a, b, c, 0, 0, 0);
}

// One wave = 16 samples (fixed b,o), loops d=0..4 accumulating the device sum.
// L1: D=A(W0f)*B(x taps). L2: D=A(W1f)*B(h1). L3: D=A(h2)*B(W2f). L4: VALU dot.
// Layer boundary transpose via wave-private LDS row, phi(u=16t+4q+r) = q*24+4t+r.
__global__ __launch_bounds__(256, 2) void mlp_kernel(
    const float* __restrict__ x, const float* __restrict__ W3, const float* __restrict__ b3,
    const float* __restrict__ biasTab, const u16* __restrict__ W0f,
    const u16* __restrict__ W1f, const u16* __restrict__ W2f, float* __restrict__ out) {
  __shared__ u16 H[4][16][104];  // [wave][sample][phi-permuted units], 208B row stride
  const int lane = threadIdx.x & 63;
  const int wv = threadIdx.x >> 6;
  const int q = lane >> 4, n = lane & 15;
  const int w = blockIdx.x * 4 + wv;  // global wave id, 0..2047

  // resident weight fragments (the whole MLP's weights live in VGPRs)
  short8 w0f[6], w1f[6][3], w2f[6][3];
  const short8* p0 = (const short8*)W0f;
  const short8* p1 = (const short8*)W1f;
  const short8* p2 = (const short8*)W2f;
#pragma unroll
  for (int t = 0; t < 6; ++t) w0f[t] = p0[t * 64 + lane];
#pragma unroll
  for (int t = 0; t < 6; ++t)
#pragma unroll
    for (int ki = 0; ki < 3; ++ki) {
      w1f[t][ki] = p1[(t * 3 + ki) * 64 + lane];
      w2f[t][ki] = p2[(t * 3 + ki) * 64 + lane];
    }
  float w3l[6];
#pragma unroll
  for (int t = 0; t < 6; ++t) {
    int u = t * 16 + n;
    w3l[t] = (u < 90) ? W3[u] : ((u == 90) ? b3[0] : 0.0f);  // b3 folded at unit 90
  }

  const int extra = 10800 - 5 * 2048;  // 560 waves take 6 tiles, rest 5
  int cnt = 5 + (w < extra ? 1 : 0);
  int base = w * 5 + (w < extra ? w : extra);

  u16* Hrow = &H[wv][n][0];
  const f32x4 z4 = {0.f, 0.f, 0.f, 0.f};

  for (int it = 0; it < cnt; ++it) {
    int sigma = base + it;
    int seg = sigma / 225;             // b*6+o
    int l0 = (sigma % 225) * 16;
    int bb = seg / 6, o = seg % 6;
    int l = l0 + n;                    // this lane's sample
    int oh = l / 60, ow = l - oh * 60;
    const float* xrow = x + (bb * 4096 + oh * 64 + ow);

    f32x4 outAcc = {0.f, 0.f, 0.f, 0.f};

    for (int d = 0; d < 5; ++d) {
      // ---- L1: B-frag = x taps (B[k=tap][n=sample]); only q==0 lanes carry taps
      short8 bx = {0, 0, 0, 0, 0, 0, 0, 0};
      if (q == 0) {
        const float* xp = xrow + d * 64;
        bx[0] = (short)f2b(xp[0]); bx[1] = (short)f2b(xp[1]); bx[2] = (short)f2b(xp[2]);
        bx[3] = (short)f2b(xp[3]); bx[4] = (short)f2b(xp[4]);
      }
      f32x4 acc[6];
#pragma unroll
      for (int t = 0; t < 6; ++t) acc[t] = mfma16(w0f[t], bx, z4);

      // bias + relu + pack -> LDS (D layout: col=lane&15=sample, row=q*4+r=unit)
      const float* bt = biasTab + (o * 5 + d) * 96;
#pragma unroll
      for (int t = 0; t < 6; t += 2) {
        f32x4 vA = acc[t] + *(const f32x4*)(bt + t * 16 + q * 4);
        f32x4 vB = acc[t + 1] + *(const f32x4*)(bt + (t + 1) * 16 + q * 4);
        uint4 pk4;
        pk4.x = pk2(fmaxf(vA.x, 0.f), fmaxf(vA.y, 0.f));
        pk4.y = pk2(fmaxf(vA.z, 0.f), fmaxf(vA.w, 0.f));
        pk4.z = pk2(fmaxf(vB.x, 0.f), fmaxf(vB.y, 0.f));
        pk4.w = pk2(fmaxf(vB.z, 0.f), fmaxf(vB.w, 0.f));
        *(uint4*)&Hrow[q * 24 + t * 4] = pk4;
      }
      lds_fence_lgkm0();
      short8 F[3];
#pragma unroll
      for (int ki = 0; ki < 3; ++ki) {
        int ph0 = (q & 1) * 48 + (ki * 2 + (q >> 1)) * 4;
        uint2 lo = *(const uint2*)&Hrow[ph0];
        uint2 hi = *(const uint2*)&Hrow[ph0 + 24];
        union { u32 u[4]; short8 s; } fu;
        fu.u[0] = lo.x; fu.u[1] = lo.y; fu.u[2] = hi.x; fu.u[3] = hi.y;
        F[ki] = fu.s;
      }
      // ---- L2: D = W1 * h1
#pragma unroll
      for (int t = 0; t < 6; ++t) {
        f32x4 a = z4;
#pragma unroll
        for (int ki = 0; ki < 3; ++ki) a = mfma16(w1f[t][ki], F[ki], a);
        acc[t] = a;
      }
      lds_fence_lgkm0();  // h1 reads complete before overwrite
#pragma unroll
      for (int t = 0; t < 6; t += 2) {
        f32x4 vA = acc[t], vB = acc[t + 1];
        uint4 pk4;
        pk4.x = pk2(fmaxf(vA.x, 0.f), fmaxf(vA.y, 0.f));
        pk4.y = pk2(fmaxf(vA.z, 0.f), fmaxf(vA.w, 0.f));
        pk4.z = pk2(fmaxf(vB.x, 0.f), fmaxf(vB.y, 0.f));
        pk4.w = pk2(fmaxf(vB.z, 0.f), fmaxf(vB.w, 0.f));
        *(uint4*)&Hrow[q * 24 + t * 4] = pk4;
      }
      lds_fence_lgkm0();
#pragma unroll
      for (int ki = 0; ki < 3; ++ki) {
        int ph0 = (q & 1) * 48 + (ki * 2 + (q >> 1)) * 4;
        uint2 lo = *(const uint2*)&Hrow[ph0];
        uint2 hi = *(const uint2*)&Hrow[ph0 + 24];
        union { u32 u[4]; short8 s; } fu;
        fu.u[0] = lo.x; fu.u[1] = lo.y; fu.u[2] = hi.x; fu.u[3] = hi.y;
        F[ki] = fu.s;
      }
      // ---- L3 (A = h2, B = W2f) + L4 dot with W3 (b3 via unit 90)
#pragma unroll
      for (int t = 0; t < 6; ++t) {
        f32x4 a = z4;
#pragma unroll
        for (int ki = 0; ki < 3; ++ki) a = mfma16(F[ki], w2f[t][ki], a);
        float w3 = w3l[t];
        outAcc.x += fmaxf(a.x, 0.f) * w3;
        outAcc.y += fmaxf(a.y, 0.f) * w3;
        outAcc.z += fmaxf(a.z, 0.f) * w3;
        outAcc.w += fmaxf(a.w, 0.f) * w3;
      }
      lds_fence_lgkm0();  // h2 reads complete before next d-iter's L1 writes
    }  // d

    // reduce over the 16 unit-lanes (samples live in (q, reg))
#pragma unroll
    for (int off = 1; off < 16; off <<= 1) {
      outAcc.x += __shfl_xor(outAcc.x, off, 64);
      outAcc.y += __shfl_xor(outAcc.y, off, 64);
      outAcc.z += __shfl_xor(outAcc.z, off, 64);
      outAcc.w += __shfl_xor(outAcc.w, off, 64);
    }
    if (n == 0) {
      *(f32x4*)&out[seg * 3600 + l0 + q * 4] = outAcc;  // samples q*4..q*4+3, fp32 out
    }
  }
}

extern "C" void kernel_launch(void* const* d_in, const int* in_sizes, int n_in,
                              void* d_out, int out_size, void* d_ws, size_t ws_size,
                              hipStream_t stream) {
  const float* x  = (const float*)d_in[0];
  const float* ac = (const float*)d_in[1];
  const float* W0 = (const float*)d_in[2];
  const float* b0 = (const float*)d_in[3];
  const float* W1 = (const float*)d_in[4];
  const float* b1 = (const float*)d_in[5];
  const float* W2 = (const float*)d_in[6];
  const float* b2 = (const float*)d_in[7];
  const float* W3 = (const float*)d_in[8];
  const float* b3 = (const float*)d_in[9];
  float* out = (float*)d_out;
  char* ws = (char*)d_ws;
  float* biasTab = (float*)(ws + WS_BIAS);
  u16* W0f = (u16*)(ws + WS_W0F);
  u16* W1f = (u16*)(ws + WS_W1F);
  u16* W2f = (u16*)(ws + WS_W2F);
  prep_kernel<<<64, 256, 0, stream>>>(ac, W0, b0, W1, b1, W2, b2, biasTab, W0f, W1f, W2f);
  mlp_kernel<<<512, 256, 0, stream>>>(x, W3, b3, biasTab, W0f, W1f, W2f, out);
}